// Round 6
// baseline (213.417 us; speedup 1.0000x reference)
//
#include <hip/hip_runtime.h>
#include <math.h>

typedef _Float16 f16;
typedef _Float16 f16x8 __attribute__((ext_vector_type(8)));
typedef float f32x4 __attribute__((ext_vector_type(4)));

#define Bn 128
#define Tn 32
#define Hn 768
#define En 4
#define Fn 3072
#define Rn 256
#define MAXT 67

static constexpr size_t OUT_ELEMS  = (size_t)Rn*Tn*Hn;
static constexpr size_t SCORES_OFF = OUT_ELEMS;
static constexpr size_t ROUTE_OFF  = OUT_ELEMS + Rn;
static constexpr size_t BIDX_OFF   = OUT_ELEMS + 2*Rn;
static constexpr size_t LOSS_OFF   = OUT_ELEMS + 3*Rn;

// ws byte offsets
#define WS_WSF    0u
#define WS_ROUTE  4096u
#define WS_GRP    8192u
#define WS_X16    16384u
#define WS_W1T    (WS_X16 + 2u*Bn*Tn*Hn)
#define WS_W2T    (WS_W1T + 2u*En*Hn*Fn)
#define WS_H1     (WS_W2T + 2u*En*Fn*Hn)

#define GLOAD16(g, l) __builtin_amdgcn_global_load_lds( \
    (const __attribute__((address_space(1))) unsigned int*)(g), \
    (__attribute__((address_space(3))) unsigned int*)(l), 16, 0, 0)

__device__ __forceinline__ float fast_gelu(float v) {
  float s = v * 0.70710678118f;
  float a = fabsf(s);
  float t = 1.0f / (1.0f + 0.3275911f * a);
  float y = t*(0.254829592f + t*(-0.284496736f + t*(1.421413741f +
            t*(-1.453152027f + t*1.061405429f))));
  float er = 1.0f - y * __expf(-a*a);
  er = (s < 0.0f) ? -er : er;
  return 0.5f * v * (1.0f + er);
}

__global__ __launch_bounds__(64) void gate_kernel(
    const float* __restrict__ x, const float* __restrict__ Wg,
    float* __restrict__ out, float* __restrict__ wsf, int* __restrict__ route)
{
  const int b = blockIdx.x;
  const int l = threadIdx.x;
  float acc0=0.f, acc1=0.f, acc2=0.f, acc3=0.f;
  const float* xb = x + (size_t)b*Tn*Hn;
  for (int h = l; h < Hn; h += 64) {
    float xa = 0.f;
    #pragma unroll
    for (int t = 0; t < Tn; ++t) xa += xb[t*Hn + h];
    xa *= (1.0f/Tn);
    acc0 += xa * Wg[0*Hn + h];
    acc1 += xa * Wg[1*Hn + h];
    acc2 += xa * Wg[2*Hn + h];
    acc3 += xa * Wg[3*Hn + h];
  }
  #pragma unroll
  for (int o = 32; o > 0; o >>= 1) {
    acc0 += __shfl_down(acc0, o);
    acc1 += __shfl_down(acc1, o);
    acc2 += __shfl_down(acc2, o);
    acc3 += __shfl_down(acc3, o);
  }
  if (l == 0) {
    float lg[4] = {acc0, acc1, acc2, acc3};
    float m = fmaxf(fmaxf(lg[0],lg[1]), fmaxf(lg[2],lg[3]));
    float p[4]; float s = 0.f;
    #pragma unroll
    for (int e = 0; e < 4; ++e) { p[e] = expf(lg[e]-m); s += p[e]; }
    float inv = 1.f/s;
    #pragma unroll
    for (int e = 0; e < 4; ++e) { p[e] *= inv; wsf[b*4+e] = p[e]; }
    int i1 = 0;
    #pragma unroll
    for (int e = 1; e < 4; ++e) if (p[e] > p[i1]) i1 = e;
    int i2 = (i1 == 0) ? 1 : 0;
    #pragma unroll
    for (int e = 0; e < 4; ++e) if (e != i1 && p[e] > p[i2]) i2 = e;
    int idx[2] = {i1, i2};
    #pragma unroll
    for (int k = 0; k < 2; ++k) {
      int r = 2*b + k;
      float pv = p[idx[k]];
      wsf[512 + r] = pv;
      route[r] = idx[k];
      out[SCORES_OFF + r] = pv;
      out[ROUTE_OFF  + r] = (float)idx[k];
      out[BIDX_OFF   + r] = (float)r;
    }
  }
}

__global__ __launch_bounds__(64) void loss_kernel(
    const float* __restrict__ wsf, float* __restrict__ out)
{
  const int l = threadIdx.x;
  float i0=0.f,i1=0.f,i2=0.f,i3=0.f;
  for (int b = l; b < Bn; b += 64) {
    i0 += wsf[b*4+0]; i1 += wsf[b*4+1]; i2 += wsf[b*4+2]; i3 += wsf[b*4+3];
  }
  #pragma unroll
  for (int o = 32; o > 0; o >>= 1) {
    i0 += __shfl_down(i0,o); i1 += __shfl_down(i1,o);
    i2 += __shfl_down(i2,o); i3 += __shfl_down(i3,o);
  }
  if (l == 0) {
    float mean = 0.25f*(i0+i1+i2+i3);
    float d0=i0-mean, d1=i1-mean, d2=i2-mean, d3=i3-mean;
    float var = (d0*d0+d1*d1+d2*d2+d3*d3) * (1.f/3.f);
    out[LOSS_OFF] = var / (mean*mean);
  }
}

// grp: [0]=ntiles; tiles at [8+3i]={e,bstart,nbeams(<=4)}; blist at [384..639]
__global__ __launch_bounds__(64) void group_kernel(
    const int* __restrict__ route, int* __restrict__ grp)
{
  const int l = threadIdx.x;
  int cnt = 0;
  if (l < 4) { for (int r = 0; r < Rn; ++r) cnt += (route[r] == l); }
  int c0 = __shfl(cnt, 0), c1 = __shfl(cnt, 1), c2 = __shfl(cnt, 2), c3 = __shfl(cnt, 3);
  int off = (l >= 1 ? c0 : 0) + (l >= 2 ? c1 : 0) + (l >= 3 ? c2 : 0);
  if (l < 4) {
    int p = off;
    for (int r = 0; r < Rn; ++r) if (route[r] == l) grp[384 + p++] = r;
  }
  if (l == 0) {
    int cs[4] = {c0, c1, c2, c3};
    int os[4] = {0, c0, c0+c1, c0+c1+c2};
    int nt = 0;
    for (int e = 0; e < 4; ++e) {
      for (int s = 0; s < cs[e]; s += 4) {
        int nb = cs[e] - s; if (nb > 4) nb = 4;
        grp[8+nt*3+0] = e; grp[8+nt*3+1] = os[e]+s; grp[8+nt*3+2] = nb;
        ++nt;
      }
    }
    grp[0] = nt;
  }
}

__global__ __launch_bounds__(256) void convx_kernel(
    const float* __restrict__ x, f16* __restrict__ x16)
{
  const int i = (blockIdx.x*256 + threadIdx.x) * 8;
  float4 a = *(const float4*)(x + i);
  float4 b = *(const float4*)(x + i + 4);
  union { f16 h[8]; uint4 u; } p;
  p.h[0]=(f16)a.x; p.h[1]=(f16)a.y; p.h[2]=(f16)a.z; p.h[3]=(f16)a.w;
  p.h[4]=(f16)b.x; p.h[5]=(f16)b.y; p.h[6]=(f16)b.z; p.h[7]=(f16)b.w;
  *(uint4*)(x16 + i) = p.u;
}

// src [E][R][C] fp32 -> dst [E][C][R] fp16.  grid (C/64, R/64, E), block 256.
__global__ __launch_bounds__(256) void transcvt_kernel(
    const float* __restrict__ src, f16* __restrict__ dst, int R, int C)
{
  __shared__ f16 t[64][74];
  const int e  = blockIdx.z;
  const int r0 = blockIdx.y*64, c0 = blockIdx.x*64;
  const float* s = src + (size_t)e*R*C;
  f16* d = dst + (size_t)e*R*C;
  const int tid = threadIdx.x;
  const int i  = tid >> 2;
  const int j0 = (tid & 3) * 16;
  #pragma unroll
  for (int q = 0; q < 16; q += 4) {
    float4 v = *(const float4*)(s + (size_t)(r0+i)*C + c0 + j0 + q);
    t[i][j0+q+0]=(f16)v.x; t[i][j0+q+1]=(f16)v.y; t[i][j0+q+2]=(f16)v.z; t[i][j0+q+3]=(f16)v.w;
  }
  __syncthreads();
  f16 o[16];
  #pragma unroll
  for (int q = 0; q < 16; ++q) o[q] = t[j0+q][i];
  *(uint4*)(d + (size_t)(c0+i)*R + r0 + j0)     = *(uint4*)&o[0];
  *(uint4*)(d + (size_t)(c0+i)*R + r0 + j0 + 8) = *(uint4*)&o[8];
}

// Grouped GEMM: BM=128 (4-beam tiles), BK=32, NWAVE waves of 64x64 wave-tiles
// (wave grid 2 x NWY).  global_load_lds + counted vmcnt + dbuf; 2-bit XOR swizzle.
// LDS: A[2][128][64B] @0; B[2][BN][64B] @16384; epilogue 64-row halves @0 (32KB).
template<int KD, int ND, int BN, int NWAVE, bool G1>
__global__ __launch_bounds__(NWAVE*64, 4) void gemm_kernel(
    const f16* __restrict__ A16, const f16* __restrict__ B16,
    const float* __restrict__ bias, f16* __restrict__ oh,
    float* __restrict__ of, const int* __restrict__ grp,
    const float* __restrict__ wsf)
{
  constexpr int NY  = ND / BN;
  constexpr int NWY = BN / 64;             // wave cols
  constexpr int BI_A = 128 / (NWAVE*16);   // A gloads/wave
  constexpr int BI_B = BN  / (NWAVE*16);   // B gloads/wave
  constexpr int NLD  = BI_A + BI_B;
  constexpr int BBUF = BN * 64;            // B buffer bytes per buf

  const int ntiles = grp[0];
  const int tix = blockIdx.x / NY;
  const int ny  = blockIdx.x % NY;
  if (tix >= ntiles) return;
  const int e      = grp[8+tix*3+0];
  const int bstart = grp[8+tix*3+1];
  const int nb     = grp[8+tix*3+2];
  const int n0     = ny * BN;
  const int tid    = threadIdx.x;
  const int lane   = tid & 63;
  const int w      = tid >> 6;

  extern __shared__ __align__(16) char smem[];

  // ---- staging sources (pre-swizzled unit: (l&3) ^ ((l>>3)&3)) ----
  const int srow  = lane >> 2;                      // 0..15 row within 16-row chunk
  const int sunit = (lane & 3) ^ ((lane >> 3) & 3); // swizzled 16B unit
  const f16* asrc[BI_A];
  #pragma unroll
  for (int i = 0; i < BI_A; ++i) {
    int row = (w*BI_A + i)*16 + srow;
    int slot = row >> 5; if (slot >= nb) slot = nb - 1;
    int beam = grp[384 + bstart + slot];
    size_t rbase = G1 ? ((size_t)(beam>>1)*Tn + (row&31)) * (size_t)KD
                      : ((size_t)beam*Tn + (row&31)) * (size_t)KD;
    asrc[i] = A16 + rbase + sunit*8;
  }
  const f16* bsrc[BI_B];
  #pragma unroll
  for (int i = 0; i < BI_B; ++i) {
    int row = (w*BI_B + i)*16 + srow;
    bsrc[i] = B16 + (size_t)e*ND*KD + (size_t)(n0 + row)*KD + sunit*8;
  }

  // ---- fragment geometry: wave (wm, wn), 64x64 tile of 16x16x32 frags ----
  const int wm = w / NWY, wn = w % NWY;
  const int lr = lane & 15, lk = lane >> 4;
  const int rowA0 = wm*64;
  const int rowB0 = wn*64;
  const int ub = (lk ^ ((lr >> 1) & 3)) << 4;   // swizzled unit byte (thread-const)

  f32x4 acc[4][4];
  #pragma unroll
  for (int i=0;i<4;++i)
    #pragma unroll
    for (int j=0;j<4;++j) acc[i][j] = (f32x4){0.f,0.f,0.f,0.f};

  constexpr int NT = KD/32;

  auto STAGE = [&](int bsel, int kt2) {
    char* Ad = smem + bsel*8192 + (w*BI_A)*1024;
    #pragma unroll
    for (int i = 0; i < BI_A; ++i) GLOAD16(asrc[i] + kt2*32, Ad + i*1024);
    char* Bd = smem + 16384 + bsel*BBUF + (w*BI_B)*1024;
    #pragma unroll
    for (int i = 0; i < BI_B; ++i) GLOAD16(bsrc[i] + kt2*32, Bd + i*1024);
  };

  STAGE(0, 0);

  int buf = 0;
  for (int kt = 0; kt < NT; ++kt) {
    if (kt + 1 < NT) {
      STAGE(buf ^ 1, kt + 1);
      asm volatile("s_waitcnt vmcnt(%0)" :: "i"(NLD) : "memory");
    } else {
      asm volatile("s_waitcnt vmcnt(0)" ::: "memory");
    }
    __builtin_amdgcn_sched_barrier(0);
    __builtin_amdgcn_s_barrier();
    __builtin_amdgcn_sched_barrier(0);

    const char* Ab = smem + buf*8192;
    const char* Bb = smem + 16384 + buf*BBUF;
    f16x8 af[4], bf[4];
    #pragma unroll
    for (int mi=0;mi<4;++mi)
      af[mi] = *(const f16x8*)(Ab + (rowA0 + mi*16 + lr)*64 + ub);
    #pragma unroll
    for (int ni=0;ni<4;++ni)
      bf[ni] = *(const f16x8*)(Bb + (rowB0 + ni*16 + lr)*64 + ub);
    __builtin_amdgcn_s_setprio(1);
    #pragma unroll
    for (int mi=0;mi<4;++mi)
      #pragma unroll
      for (int ni=0;ni<4;++ni)
        acc[mi][ni] = __builtin_amdgcn_mfma_f32_16x16x32_f16(af[mi], bf[ni], acc[mi][ni], 0, 0, 0);
    __builtin_amdgcn_s_setprio(0);
    __builtin_amdgcn_s_barrier();
    __builtin_amdgcn_sched_barrier(0);
    buf ^= 1;
  }

  // ---- epilogue: two 64-row halves through 32 KB swizzled LDS ----
  const int nvalid = nb * Tn;
  char* cst = smem;
  float bvals[4];
  if (G1) {
    #pragma unroll
    for (int ni=0;ni<4;++ni) bvals[ni] = bias[e*ND + n0 + rowB0 + ni*16 + lr];
  }

  #pragma unroll
  for (int h = 0; h < 2; ++h) {
    if (wm == h) {
      #pragma unroll
      for (int mi=0;mi<4;++mi){
        #pragma unroll
        for (int j=0;j<4;++j){
          const int m = mi*16 + (lane>>4)*4 + j;      // row within half
          const int m7 = m & 7;
          #pragma unroll
          for (int ni=0;ni<4;++ni){
            const int n = rowB0 + ni*16 + lr;
            if (G1) {
              float v = acc[mi][ni][j] + bvals[ni];
              *(f16*)(cst + m*512 + (((n>>3)^m7)<<4) + (n&7)*2) = (f16)fast_gelu(v);
            } else {
              *(float*)(cst + m*512 + (((n>>2)^m7)<<4) + (n&3)*4) = acc[mi][ni][j];
            }
          }
        }
      }
    }
    __syncthreads();
    const int u  = tid & 31;
    const int tr = tid >> 5;
    constexpr int RPI = NWAVE*2;             // rows per iteration
    #pragma unroll
    for (int it = 0; it < 64/RPI; ++it) {
      const int rl = it*RPI + tr;            // row within half
      const int r  = h*64 + rl;              // row within tile
      if (r < nvalid) {
        const int beam = grp[384 + bstart + (r>>5)];
        if (G1) {
          uint4 v = *(const uint4*)(cst + rl*512 + (((u&24)|((u&7)^(rl&7)))<<4));
          *(uint4*)(oh + ((size_t)beam*Tn + (r&31))*(size_t)ND + n0 + u*8) = v;
        } else {
          float4 b4 = *(const float4*)(bias + e*ND + n0 + u*4);
          const float sc = wsf[512 + beam];
          float4 v = *(const float4*)(cst + rl*512 + (((u&24)|((u&7)^(rl&7)))<<4));
          v.x = (v.x + b4.x)*sc; v.y = (v.y + b4.y)*sc;
          v.z = (v.z + b4.z)*sc; v.w = (v.w + b4.w)*sc;
          *(float4*)(of + ((size_t)beam*Tn + (r&31))*(size_t)Hn + n0 + u*4) = v;
        }
      }
    }
    __syncthreads();
  }
}

extern "C" void kernel_launch(void* const* d_in, const int* in_sizes, int n_in,
                              void* d_out, int out_size, void* d_ws, size_t ws_size,
                              hipStream_t stream)
{
  const float* x  = (const float*)d_in[0];
  const float* Wg = (const float*)d_in[1];
  const float* W1 = (const float*)d_in[2];
  const float* b1 = (const float*)d_in[3];
  const float* W2 = (const float*)d_in[4];
  const float* b2 = (const float*)d_in[5];
  float* out = (float*)d_out;
  char* ws = (char*)d_ws;
  float* wsf  = (float*)(ws + WS_WSF);
  int*   route= (int*)(ws + WS_ROUTE);
  int*   grp  = (int*)(ws + WS_GRP);
  f16*   x16  = (f16*)(ws + WS_X16);
  f16*   w1t  = (f16*)(ws + WS_W1T);
  f16*   w2t  = (f16*)(ws + WS_W2T);
  f16*   h1   = (f16*)(ws + WS_H1);

  gate_kernel<<<Bn, 64, 0, stream>>>(x, Wg, out, wsf, route);
  group_kernel<<<1, 64, 0, stream>>>(route, grp);
  loss_kernel<<<1, 64, 0, stream>>>(wsf, out);
  convx_kernel<<<1536, 256, 0, stream>>>(x, x16);
  transcvt_kernel<<<dim3(48,12,4), 256, 0, stream>>>(W1, w1t, Hn, Fn);
  transcvt_kernel<<<dim3(12,48,4), 256, 0, stream>>>(W2, w2t, Fn, Hn);

  auto g1 = gemm_kernel<Hn, Fn, 256, 8, true>;    // 512 thr, LDS 48KB
  auto g2 = gemm_kernel<Fn, Hn, 128, 4, false>;   // 256 thr, LDS 32KB
  const int sm1 = 49152;
  const int sm2 = 32768;
  hipFuncSetAttribute((const void*)g1, hipFuncAttributeMaxDynamicSharedMemorySize, sm1);
  hipFuncSetAttribute((const void*)g2, hipFuncAttributeMaxDynamicSharedMemorySize, sm2);
  g1<<<MAXT*12, 512, sm1, stream>>>(x16, w1t, b1, h1, nullptr, grp, wsf);
  g2<<<MAXT*6,  256, sm2, stream>>>(h1, w2t, b2, nullptr, out, grp, wsf);
}

// Round 7
// 212.893 us; speedup vs baseline: 1.0025x; 1.0025x over previous
//
#include <hip/hip_runtime.h>
#include <math.h>

typedef _Float16 f16;
typedef _Float16 f16x8 __attribute__((ext_vector_type(8)));
typedef float f32x4 __attribute__((ext_vector_type(4)));

#define Bn 128
#define Tn 32
#define Hn 768
#define En 4
#define Fn 3072
#define Rn 256
#define MAXT 67

static constexpr size_t OUT_ELEMS  = (size_t)Rn*Tn*Hn;
static constexpr size_t SCORES_OFF = OUT_ELEMS;
static constexpr size_t ROUTE_OFF  = OUT_ELEMS + Rn;
static constexpr size_t BIDX_OFF   = OUT_ELEMS + 2*Rn;
static constexpr size_t LOSS_OFF   = OUT_ELEMS + 3*Rn;

// ws byte offsets
#define WS_WSF    0u
#define WS_ROUTE  4096u
#define WS_GRP    8192u
#define WS_X16    16384u
#define WS_W1T    (WS_X16 + 2u*Bn*Tn*Hn)
#define WS_W2T    (WS_W1T + 2u*En*Hn*Fn)
#define WS_H1     (WS_W2T + 2u*En*Fn*Hn)

#define GLOAD16(g, l) __builtin_amdgcn_global_load_lds( \
    (const __attribute__((address_space(1))) unsigned int*)(g), \
    (__attribute__((address_space(3))) unsigned int*)(l), 16, 0, 0)

__device__ __forceinline__ float fast_gelu(float v) {
  float s = v * 0.70710678118f;
  float a = fabsf(s);
  float t = 1.0f / (1.0f + 0.3275911f * a);
  float y = t*(0.254829592f + t*(-0.284496736f + t*(1.421413741f +
            t*(-1.453152027f + t*1.061405429f))));
  float er = 1.0f - y * __expf(-a*a);
  er = (s < 0.0f) ? -er : er;
  return 0.5f * v * (1.0f + er);
}

__global__ __launch_bounds__(64) void gate_kernel(
    const float* __restrict__ x, const float* __restrict__ Wg,
    float* __restrict__ out, float* __restrict__ wsf, int* __restrict__ route)
{
  const int b = blockIdx.x;
  const int l = threadIdx.x;
  float acc0=0.f, acc1=0.f, acc2=0.f, acc3=0.f;
  const float* xb = x + (size_t)b*Tn*Hn;
  for (int h = l; h < Hn; h += 64) {
    float xa = 0.f;
    #pragma unroll
    for (int t = 0; t < Tn; ++t) xa += xb[t*Hn + h];
    xa *= (1.0f/Tn);
    acc0 += xa * Wg[0*Hn + h];
    acc1 += xa * Wg[1*Hn + h];
    acc2 += xa * Wg[2*Hn + h];
    acc3 += xa * Wg[3*Hn + h];
  }
  #pragma unroll
  for (int o = 32; o > 0; o >>= 1) {
    acc0 += __shfl_down(acc0, o);
    acc1 += __shfl_down(acc1, o);
    acc2 += __shfl_down(acc2, o);
    acc3 += __shfl_down(acc3, o);
  }
  if (l == 0) {
    float lg[4] = {acc0, acc1, acc2, acc3};
    float m = fmaxf(fmaxf(lg[0],lg[1]), fmaxf(lg[2],lg[3]));
    float p[4]; float s = 0.f;
    #pragma unroll
    for (int e = 0; e < 4; ++e) { p[e] = expf(lg[e]-m); s += p[e]; }
    float inv = 1.f/s;
    #pragma unroll
    for (int e = 0; e < 4; ++e) { p[e] *= inv; wsf[b*4+e] = p[e]; }
    int i1 = 0;
    #pragma unroll
    for (int e = 1; e < 4; ++e) if (p[e] > p[i1]) i1 = e;
    int i2 = (i1 == 0) ? 1 : 0;
    #pragma unroll
    for (int e = 0; e < 4; ++e) if (e != i1 && p[e] > p[i2]) i2 = e;
    int idx[2] = {i1, i2};
    #pragma unroll
    for (int k = 0; k < 2; ++k) {
      int r = 2*b + k;
      float pv = p[idx[k]];
      wsf[512 + r] = pv;
      route[r] = idx[k];
      out[SCORES_OFF + r] = pv;
      out[ROUTE_OFF  + r] = (float)idx[k];
      out[BIDX_OFF   + r] = (float)r;
    }
  }
}

__global__ __launch_bounds__(64) void loss_kernel(
    const float* __restrict__ wsf, float* __restrict__ out)
{
  const int l = threadIdx.x;
  float i0=0.f,i1=0.f,i2=0.f,i3=0.f;
  for (int b = l; b < Bn; b += 64) {
    i0 += wsf[b*4+0]; i1 += wsf[b*4+1]; i2 += wsf[b*4+2]; i3 += wsf[b*4+3];
  }
  #pragma unroll
  for (int o = 32; o > 0; o >>= 1) {
    i0 += __shfl_down(i0,o); i1 += __shfl_down(i1,o);
    i2 += __shfl_down(i2,o); i3 += __shfl_down(i3,o);
  }
  if (l == 0) {
    float mean = 0.25f*(i0+i1+i2+i3);
    float d0=i0-mean, d1=i1-mean, d2=i2-mean, d3=i3-mean;
    float var = (d0*d0+d1*d1+d2*d2+d3*d3) * (1.f/3.f);
    out[LOSS_OFF] = var / (mean*mean);
  }
}

// grp: [0]=ntiles; tiles at [8+3i]={e,bstart,nbeams(<=4)}; blist at [384..639]
__global__ __launch_bounds__(64) void group_kernel(
    const int* __restrict__ route, int* __restrict__ grp)
{
  const int l = threadIdx.x;
  int cnt = 0;
  if (l < 4) { for (int r = 0; r < Rn; ++r) cnt += (route[r] == l); }
  int c0 = __shfl(cnt, 0), c1 = __shfl(cnt, 1), c2 = __shfl(cnt, 2), c3 = __shfl(cnt, 3);
  int off = (l >= 1 ? c0 : 0) + (l >= 2 ? c1 : 0) + (l >= 3 ? c2 : 0);
  if (l < 4) {
    int p = off;
    for (int r = 0; r < Rn; ++r) if (route[r] == l) grp[384 + p++] = r;
  }
  if (l == 0) {
    int cs[4] = {c0, c1, c2, c3};
    int os[4] = {0, c0, c0+c1, c0+c1+c2};
    int nt = 0;
    for (int e = 0; e < 4; ++e) {
      for (int s = 0; s < cs[e]; s += 4) {
        int nb = cs[e] - s; if (nb > 4) nb = 4;
        grp[8+nt*3+0] = e; grp[8+nt*3+1] = os[e]+s; grp[8+nt*3+2] = nb;
        ++nt;
      }
    }
    grp[0] = nt;
  }
}

__global__ __launch_bounds__(256) void convx_kernel(
    const float* __restrict__ x, f16* __restrict__ x16)
{
  const int i = (blockIdx.x*256 + threadIdx.x) * 8;
  float4 a = *(const float4*)(x + i);
  float4 b = *(const float4*)(x + i + 4);
  union { f16 h[8]; uint4 u; } p;
  p.h[0]=(f16)a.x; p.h[1]=(f16)a.y; p.h[2]=(f16)a.z; p.h[3]=(f16)a.w;
  p.h[4]=(f16)b.x; p.h[5]=(f16)b.y; p.h[6]=(f16)b.z; p.h[7]=(f16)b.w;
  *(uint4*)(x16 + i) = p.u;
}

// src [E][R][C] fp32 -> dst [E][C][R] fp16.  grid (C/64, R/64, E), block 256.
__global__ __launch_bounds__(256) void transcvt_kernel(
    const float* __restrict__ src, f16* __restrict__ dst, int R, int C)
{
  __shared__ f16 t[64][74];
  const int e  = blockIdx.z;
  const int r0 = blockIdx.y*64, c0 = blockIdx.x*64;
  const float* s = src + (size_t)e*R*C;
  f16* d = dst + (size_t)e*R*C;
  const int tid = threadIdx.x;
  const int i  = tid >> 2;
  const int j0 = (tid & 3) * 16;
  #pragma unroll
  for (int q = 0; q < 16; q += 4) {
    float4 v = *(const float4*)(s + (size_t)(r0+i)*C + c0 + j0 + q);
    t[i][j0+q+0]=(f16)v.x; t[i][j0+q+1]=(f16)v.y; t[i][j0+q+2]=(f16)v.z; t[i][j0+q+3]=(f16)v.w;
  }
  __syncthreads();
  f16 o[16];
  #pragma unroll
  for (int q = 0; q < 16; ++q) o[q] = t[j0+q][i];
  *(uint4*)(d + (size_t)(c0+i)*R + r0 + j0)     = *(uint4*)&o[0];
  *(uint4*)(d + (size_t)(c0+i)*R + r0 + j0 + 8) = *(uint4*)&o[8];
}

// Grouped GEMM: BM=128 (4-beam tiles), BK=32, NWAVE waves of 64x64 wave-tiles.
// Triple-buffered global_load_lds pipeline, ONE barrier + counted vmcnt per
// K-step, depth-2 prefetch.  2-bit XOR swizzle both-sides.
// LDS: buf b at b*BUFSZ: A[128][64B] then B[BN][64B].  Epilogue reuses 32KB.
template<int KD, int ND, int BN, int NWAVE, bool G1>
__global__ __launch_bounds__(NWAVE*64, 4) void gemm_kernel(
    const f16* __restrict__ A16, const f16* __restrict__ B16,
    const float* __restrict__ bias, f16* __restrict__ oh,
    float* __restrict__ of, const int* __restrict__ grp,
    const float* __restrict__ wsf)
{
  constexpr int NY  = ND / BN;
  constexpr int NWY = BN / 64;             // wave cols
  constexpr int BI_A = 128 / (NWAVE*16);   // A gloads/wave
  constexpr int BI_B = BN  / (NWAVE*16);   // B gloads/wave
  constexpr int NLD  = BI_A + BI_B;
  constexpr int BUFSZ = (128 + BN) * 64;   // bytes per buffer (A then B)

  const int ntiles = grp[0];
  const int tix = blockIdx.x / NY;
  const int ny  = blockIdx.x % NY;
  if (tix >= ntiles) return;
  const int e      = grp[8+tix*3+0];
  const int bstart = grp[8+tix*3+1];
  const int nb     = grp[8+tix*3+2];
  const int n0     = ny * BN;
  const int tid    = threadIdx.x;
  const int lane   = tid & 63;
  const int w      = tid >> 6;

  extern __shared__ __align__(16) char smem[];

  // ---- staging sources (pre-swizzled unit: (l&3) ^ ((l>>3)&3)) ----
  const int srow  = lane >> 2;                      // row within 16-row chunk
  const int sunit = (lane & 3) ^ ((lane >> 3) & 3); // swizzled 16B unit
  const f16* asrc[BI_A];
  #pragma unroll
  for (int i = 0; i < BI_A; ++i) {
    int row = (w*BI_A + i)*16 + srow;
    int slot = row >> 5; if (slot >= nb) slot = nb - 1;
    int beam = grp[384 + bstart + slot];
    size_t rbase = G1 ? ((size_t)(beam>>1)*Tn + (row&31)) * (size_t)KD
                      : ((size_t)beam*Tn + (row&31)) * (size_t)KD;
    asrc[i] = A16 + rbase + sunit*8;
  }
  const f16* bsrc[BI_B];
  #pragma unroll
  for (int i = 0; i < BI_B; ++i) {
    int row = (w*BI_B + i)*16 + srow;
    bsrc[i] = B16 + (size_t)e*ND*KD + (size_t)(n0 + row)*KD + sunit*8;
  }

  // ---- fragment geometry ----
  const int wm = w / NWY, wn = w % NWY;
  const int lr = lane & 15, lk = lane >> 4;
  const int rowA0 = wm*64;
  const int rowB0 = wn*64;
  const int ub = (lk ^ ((lr >> 1) & 3)) << 4;

  f32x4 acc[4][4];
  #pragma unroll
  for (int i=0;i<4;++i)
    #pragma unroll
    for (int j=0;j<4;++j) acc[i][j] = (f32x4){0.f,0.f,0.f,0.f};

  constexpr int NT = KD/32;          // 24 (g1) / 96 (g2); both %3 == 0
  static_assert(NT % 3 == 0, "NT must be divisible by 3");

  auto STAGE = [&](int bsel, int kt2) {
    char* Ad = smem + bsel*BUFSZ + (w*BI_A)*1024;
    #pragma unroll
    for (int i = 0; i < BI_A; ++i) GLOAD16(asrc[i] + kt2*32, Ad + i*1024);
    char* Bd = smem + bsel*BUFSZ + 8192 + (w*BI_B)*1024;
    #pragma unroll
    for (int i = 0; i < BI_B; ++i) GLOAD16(bsrc[i] + kt2*32, Bd + i*1024);
  };

  auto COMPUTE = [&](int b) {
    const char* Ab = smem + b*BUFSZ;
    const char* Bb = Ab + 8192;
    f16x8 af[4], bf[4];
    #pragma unroll
    for (int mi=0;mi<4;++mi)
      af[mi] = *(const f16x8*)(Ab + (rowA0 + mi*16 + lr)*64 + ub);
    #pragma unroll
    for (int ni=0;ni<4;++ni)
      bf[ni] = *(const f16x8*)(Bb + (rowB0 + ni*16 + lr)*64 + ub);
    __builtin_amdgcn_s_setprio(1);
    #pragma unroll
    for (int mi=0;mi<4;++mi)
      #pragma unroll
      for (int ni=0;ni<4;++ni)
        acc[mi][ni] = __builtin_amdgcn_mfma_f32_16x16x32_f16(af[mi], bf[ni], acc[mi][ni], 0, 0, 0);
    __builtin_amdgcn_s_setprio(0);
  };

  // ---- pipeline: prologue stages tiles 0,1 ----
  STAGE(0, 0);
  STAGE(1, 1);

#define STEP(B, SB, KT2, VM, DOSTAGE) do { \
    asm volatile("s_waitcnt vmcnt(%0)" :: "i"(VM) : "memory"); \
    __builtin_amdgcn_sched_barrier(0); \
    __builtin_amdgcn_s_barrier(); \
    __builtin_amdgcn_sched_barrier(0); \
    if (DOSTAGE) STAGE(SB, KT2); \
    COMPUTE(B); \
  } while (0)

  for (int kt = 0; kt + 6 <= NT; kt += 3) {
    STEP(0, 2, kt+2, NLD, true);
    STEP(1, 0, kt+3, NLD, true);
    STEP(2, 1, kt+4, NLD, true);
  }
  // tail: k = NT-3, NT-2, NT-1  (bufs 0,1,2 since NT%3==0)
  STEP(0, 2, NT-1, NLD, true);
  STEP(1, 0, 0,    NLD, false);
  STEP(2, 0, 0,    0,   false);
#undef STEP

  __builtin_amdgcn_s_barrier();   // all waves done reading bufs before reuse

  // ---- epilogue: two 64-row halves through 32 KB swizzled LDS ----
  const int nvalid = nb * Tn;
  char* cst = smem;
  float bvals[4];
  if (G1) {
    #pragma unroll
    for (int ni=0;ni<4;++ni) bvals[ni] = bias[e*ND + n0 + rowB0 + ni*16 + lr];
  }

  #pragma unroll
  for (int h = 0; h < 2; ++h) {
    if (wm == h) {
      #pragma unroll
      for (int mi=0;mi<4;++mi){
        #pragma unroll
        for (int j=0;j<4;++j){
          const int m = mi*16 + (lane>>4)*4 + j;      // row within half
          const int m7 = m & 7;
          #pragma unroll
          for (int ni=0;ni<4;++ni){
            const int n = rowB0 + ni*16 + lr;
            if (G1) {
              float v = acc[mi][ni][j] + bvals[ni];
              *(f16*)(cst + m*512 + (((n>>3)^m7)<<4) + (n&7)*2) = (f16)fast_gelu(v);
            } else {
              *(float*)(cst + m*512 + (((n>>2)^m7)<<4) + (n&3)*4) = acc[mi][ni][j];
            }
          }
        }
      }
    }
    __syncthreads();
    const int u  = tid & 31;
    const int tr = tid >> 5;
    float4 b4;
    if (!G1) b4 = *(const float4*)(bias + e*ND + n0 + u*4);
    constexpr int RPI = NWAVE*2;             // rows per iteration
    #pragma unroll
    for (int it = 0; it < 64/RPI; ++it) {
      const int rl = it*RPI + tr;            // row within half
      const int r  = h*64 + rl;              // row within tile
      if (r < nvalid) {
        const int beam = grp[384 + bstart + (r>>5)];
        if (G1) {
          uint4 v = *(const uint4*)(cst + rl*512 + (((u&24)|((u&7)^(rl&7)))<<4));
          *(uint4*)(oh + ((size_t)beam*Tn + (r&31))*(size_t)ND + n0 + u*8) = v;
        } else {
          const float sc = wsf[512 + beam];
          float4 v = *(const float4*)(cst + rl*512 + (((u&24)|((u&7)^(rl&7)))<<4));
          v.x = (v.x + b4.x)*sc; v.y = (v.y + b4.y)*sc;
          v.z = (v.z + b4.z)*sc; v.w = (v.w + b4.w)*sc;
          *(float4*)(of + ((size_t)beam*Tn + (r&31))*(size_t)Hn + n0 + u*4) = v;
        }
      }
    }
    __syncthreads();
  }
}

extern "C" void kernel_launch(void* const* d_in, const int* in_sizes, int n_in,
                              void* d_out, int out_size, void* d_ws, size_t ws_size,
                              hipStream_t stream)
{
  const float* x  = (const float*)d_in[0];
  const float* Wg = (const float*)d_in[1];
  const float* W1 = (const float*)d_in[2];
  const float* b1 = (const float*)d_in[3];
  const float* W2 = (const float*)d_in[4];
  const float* b2 = (const float*)d_in[5];
  float* out = (float*)d_out;
  char* ws = (char*)d_ws;
  float* wsf  = (float*)(ws + WS_WSF);
  int*   route= (int*)(ws + WS_ROUTE);
  int*   grp  = (int*)(ws + WS_GRP);
  f16*   x16  = (f16*)(ws + WS_X16);
  f16*   w1t  = (f16*)(ws + WS_W1T);
  f16*   w2t  = (f16*)(ws + WS_W2T);
  f16*   h1   = (f16*)(ws + WS_H1);

  gate_kernel<<<Bn, 64, 0, stream>>>(x, Wg, out, wsf, route);
  group_kernel<<<1, 64, 0, stream>>>(route, grp);
  loss_kernel<<<1, 64, 0, stream>>>(wsf, out);
  convx_kernel<<<1536, 256, 0, stream>>>(x, x16);
  transcvt_kernel<<<dim3(48,12,4), 256, 0, stream>>>(W1, w1t, Hn, Fn);
  transcvt_kernel<<<dim3(12,48,4), 256, 0, stream>>>(W2, w2t, Fn, Hn);

  auto g1 = gemm_kernel<Hn, Fn, 256, 8, true>;    // 512 thr, LDS 72KB -> 2 blk/CU
  auto g2 = gemm_kernel<Fn, Hn, 128, 4, false>;   // 256 thr, LDS 48KB -> 3 blk/CU
  const int sm1 = 3 * (128 + 256) * 64;   // 73728
  const int sm2 = 3 * (128 + 128) * 64;   // 49152
  hipFuncSetAttribute((const void*)g1, hipFuncAttributeMaxDynamicSharedMemorySize, sm1);
  hipFuncSetAttribute((const void*)g2, hipFuncAttributeMaxDynamicSharedMemorySize, sm2);
  g1<<<MAXT*12, 512, sm1, stream>>>(x16, w1t, b1, h1, nullptr, grp, wsf);
  g2<<<MAXT*6,  256, sm2, stream>>>(h1, w2t, b2, nullptr, out, grp, wsf);
}